// Round 9
// baseline (319.459 us; speedup 1.0000x reference)
//
#include <hip/hip_runtime.h>
#include <math.h>

#define NEG_SLOPE 0.2f

typedef __attribute__((ext_vector_type(8))) short short8;   // 8 bf16 (4 VGPRs)
typedef __attribute__((ext_vector_type(4))) float f32x4;
typedef __attribute__((ext_vector_type(2))) float f32x2;    // v_pk_*_f32 ops

__device__ __forceinline__ int imin(int a, int b) { return a < b ? a : b; }

__device__ __forceinline__ unsigned int f2bf(float f) {
    unsigned int u = __float_as_uint(f);
    return (u + 0x7fffu + ((u >> 16) & 1u)) >> 16;   // RNE
}
__device__ __forceinline__ f32x2 bfpair(unsigned int u) {
    f32x2 r;
    r.x = __uint_as_float(u << 16);
    r.y = __uint_as_float(u & 0xffff0000u);
    return r;
}
template <int CTRL>
__device__ __forceinline__ float dpp_add(float v) {
    int t = __builtin_amdgcn_update_dpp(0, __float_as_int(v), CTRL, 0xF, 0xF, true);
    return v + __int_as_float(t);
}

// ---------------------------------------------------------------------------
// Kernel 1: packed histogram. One 64-bit atomic per edge onto a 64B-padded
// slot: low 32 = count, high 32 = ea sum in 2^-16 fixed point.
// ---------------------------------------------------------------------------
__global__ void edge_hist(const int* __restrict__ ei, const float* __restrict__ ea,
                          unsigned long long* __restrict__ hist, int E) {
    int e = blockIdx.x * blockDim.x + threadIdx.x;
    if (e < E) {
        int d = ei[E + e];
        long long fx = (long long)__float2int_rn(ea[e] * 65536.0f);
        unsigned long long v = ((unsigned long long)fx << 32) | 1ull;
        atomicAdd(&hist[(size_t)d * 8], v);
    }
}

// ---------------------------------------------------------------------------
// 3-phase parallel scan over hist (padded stride 8).
// ---------------------------------------------------------------------------
__global__ void scan_a(const unsigned long long* __restrict__ hist, int* __restrict__ bsum, int n) {
    __shared__ int wred[4];
    int base = blockIdx.x * 1024;
    int tid = threadIdx.x;
    int s = 0;
#pragma unroll
    for (int k = 0; k < 4; ++k) {
        int i = base + tid + k * 256;
        if (i < n) s += (int)(hist[(size_t)i * 8] & 0xffffffffull);
    }
#pragma unroll
    for (int off = 32; off > 0; off >>= 1) s += __shfl_xor(s, off, 64);
    if ((tid & 63) == 0) wred[tid >> 6] = s;
    __syncthreads();
    if (tid == 0) bsum[blockIdx.x] = wred[0] + wred[1] + wred[2] + wred[3];
}

__global__ void scan_b(int* __restrict__ bsum, int* __restrict__ row_ptr, int B, int n) {
    int tid = threadIdx.x;           // 64 threads, B <= 64
    int v = (tid < B) ? bsum[tid] : 0;
    int s = v;
#pragma unroll
    for (int off = 1; off < 64; off <<= 1) {
        int t = __shfl_up(s, off, 64);
        if (tid >= off) s += t;
    }
    if (tid < B) bsum[tid] = s - v;  // exclusive
    if (tid == 63) row_ptr[n] = s;   // total
}

__global__ void scan_c(const unsigned long long* __restrict__ hist,
                       const int* __restrict__ bsum, int* __restrict__ row_ptr,
                       int* __restrict__ wptr_pad, float* __restrict__ ea_loop, int n) {
    __shared__ int wtot[4];
    int tid = threadIdx.x;
    int wid = tid >> 6, lane = tid & 63;
    int i0 = blockIdx.x * 1024 + tid * 4;
    int dcnt[4]; float esum[4];
#pragma unroll
    for (int k = 0; k < 4; ++k) {
        if (i0 + k < n) {
            unsigned long long h = hist[(size_t)(i0 + k) * 8];
            dcnt[k] = (int)(h & 0xffffffffull);
            esum[k] = (float)((int)(h >> 32)) * (1.0f / 65536.0f);
        } else { dcnt[k] = 0; esum[k] = 0.0f; }
    }
    int tsum = dcnt[0] + dcnt[1] + dcnt[2] + dcnt[3];
    int s = tsum;
#pragma unroll
    for (int off = 1; off < 64; off <<= 1) {
        int t = __shfl_up(s, off, 64);
        if (lane >= off) s += t;
    }
    if (lane == 63) wtot[wid] = s;
    __syncthreads();
    int wpre = 0;
#pragma unroll
    for (int k = 0; k < 4; ++k) if (k < wid) wpre += wtot[k];
    int pre = bsum[blockIdx.x] + wpre + (s - tsum);
    if (i0 < n) {
        int4 e;
        e.x = pre;
        e.y = pre + dcnt[0];
        e.z = e.y + dcnt[1];
        e.w = e.z + dcnt[2];
        *(int4*)(row_ptr + i0) = e;
        int ev[4] = { e.x, e.y, e.z, e.w };
        float4 el;
        el.x = esum[0] / fmaxf((float)dcnt[0], 1.0f);
        el.y = esum[1] / fmaxf((float)dcnt[1], 1.0f);
        el.z = esum[2] / fmaxf((float)dcnt[2], 1.0f);
        el.w = esum[3] / fmaxf((float)dcnt[3], 1.0f);
        *(float4*)(ea_loop + i0) = el;
#pragma unroll
        for (int k = 0; k < 4; ++k) wptr_pad[(size_t)(i0 + k) * 16] = ev[k];
    }
}

// ---------------------------------------------------------------------------
// Kernel 3: scatter edges into CSR order; (src,w) packed as int2.
// ---------------------------------------------------------------------------
__global__ void edge_scatter(const int* __restrict__ ei, const float* __restrict__ ea,
                             int* __restrict__ wptr_pad, int2* __restrict__ spk, int E) {
    int e = blockIdx.x * blockDim.x + threadIdx.x;
    if (e < E) {
        int d = ei[E + e];
        int pos = atomicAdd(&wptr_pad[(size_t)d * 16], 1);
        spk[pos] = make_int2(ei[e], __float_as_int(ea[e]));
    }
}

// ---------------------------------------------------------------------------
// Conversion: x -> bf16 vec4
// ---------------------------------------------------------------------------
__global__ void cvt_bf16_v4(const float* __restrict__ in, unsigned short* __restrict__ out, int sz4) {
    int i = blockIdx.x * blockDim.x + threadIdx.x;
    if (i < sz4) {
        float4 v = ((const float4*)in)[i];
        uint2 r;
        r.x = f2bf(v.x) | (f2bf(v.y) << 16);
        r.y = f2bf(v.z) | (f2bf(v.w) << 16);
        ((uint2*)out)[i] = r;
    }
}

// ---------------------------------------------------------------------------
// Fused weight prep: 4 transposed bf16 conversions + 2 bias concats in ONE
// launch.  Layout (flat index i):
//   [0, S1)        W1l [F,HC1]   -> Wt1 (transposed [HC1,F])
//   [S1, 2S1)      W1r           -> Wt1 + HC1*F
//   [2S1, 2S1+S2)  W2l [HC1,HC2] -> Wt2
//   [.., +S2)      W2r           -> Wt2 + HC2*HC1
//   then b1cat (2*HC1), b2cat (2*HC2)
// ---------------------------------------------------------------------------
__global__ void prep_weights(const float* __restrict__ W1l, const float* __restrict__ W1r,
                             const float* __restrict__ W2l, const float* __restrict__ W2r,
                             const float* __restrict__ b1l, const float* __restrict__ b1r,
                             const float* __restrict__ b2l, const float* __restrict__ b2r,
                             unsigned short* __restrict__ Wt1, unsigned short* __restrict__ Wt2,
                             float* __restrict__ b1cat, float* __restrict__ b2cat,
                             int F, int HC1, int HC2) {
    int S1 = F * HC1, S2 = HC1 * HC2;
    int i = blockIdx.x * blockDim.x + threadIdx.x;
    if (i < S1) {
        int k = i / HC1, nn = i - k * HC1;
        Wt1[(size_t)nn * F + k] = (unsigned short)f2bf(W1l[i]);
    } else if (i < 2 * S1) {
        int j = i - S1;
        int k = j / HC1, nn = j - k * HC1;
        Wt1[(size_t)(HC1 + nn) * F + k] = (unsigned short)f2bf(W1r[j]);
    } else if (i < 2 * S1 + S2) {
        int j = i - 2 * S1;
        int k = j / HC2, nn = j - k * HC2;
        Wt2[(size_t)nn * HC1 + k] = (unsigned short)f2bf(W2l[j]);
    } else if (i < 2 * S1 + 2 * S2) {
        int j = i - 2 * S1 - S2;
        int k = j / HC2, nn = j - k * HC2;
        Wt2[(size_t)(HC2 + nn) * HC1 + k] = (unsigned short)f2bf(W2r[j]);
    } else if (i < 2 * S1 + 2 * S2 + 2 * HC1) {
        int j = i - 2 * S1 - 2 * S2;
        b1cat[j] = (j < HC1) ? b1l[j] : b1r[j - HC1];
    } else if (i < 2 * S1 + 2 * S2 + 2 * HC1 + 2 * HC2) {
        int j = i - 2 * S1 - 2 * S2 - 2 * HC1;
        b2cat[j] = (j < HC2) ? b2l[j] : b2r[j - HC2];
    }
}

// ---------------------------------------------------------------------------
// Kernel 4: bf16 MFMA GEMM + bias (B pre-transposed), 64x64 tile, BK=32.
// ---------------------------------------------------------------------------
__global__ void __launch_bounds__(256)
gemm_bf16(const unsigned short* __restrict__ A, const unsigned short* __restrict__ Bt,
          const float* __restrict__ bias, unsigned short* __restrict__ C,
          int M, int N, int K) {
    __shared__ __attribute__((aligned(16))) unsigned short As[64 * 40];
    __shared__ __attribute__((aligned(16))) unsigned short Bs[64 * 40];
    int tid  = threadIdx.x;
    int wave = tid >> 6, lane = tid & 63;
    int m0 = blockIdx.x * 64, n0 = blockIdx.y * 64;
    int row = tid >> 2, kg = (tid & 3) * 8;

    f32x4 acc[4] = {};
    for (int kk = 0; kk < K; kk += 32) {
        int gm = m0 + row;
        uint4 av;
        if (gm < M) av = *(const uint4*)(A + (size_t)gm * K + kk + kg);
        else        av = make_uint4(0, 0, 0, 0);
        *(uint4*)&As[row * 40 + kg] = av;
        uint4 bv = *(const uint4*)(Bt + (size_t)(n0 + row) * K + kk + kg);
        *(uint4*)&Bs[row * 40 + kg] = bv;
        __syncthreads();
        short8 a = *(const short8*)&As[(wave * 16 + (lane & 15)) * 40 + (lane >> 4) * 8];
#pragma unroll
        for (int g = 0; g < 4; ++g) {
            short8 b = *(const short8*)&Bs[(g * 16 + (lane & 15)) * 40 + (lane >> 4) * 8];
            acc[g] = __builtin_amdgcn_mfma_f32_16x16x32_bf16(a, b, acc[g], 0, 0, 0);
        }
        __syncthreads();
    }
#pragma unroll
    for (int g = 0; g < 4; ++g) {
        int col = n0 + g * 16 + (lane & 15);
        float bs = bias[col];
#pragma unroll
        for (int r = 0; r < 4; ++r) {
            int grow = m0 + wave * 16 + (lane >> 4) * 4 + r;
            if (grow < M) C[(size_t)grow * N + col] = (unsigned short)f2bf(acc[g][r] + bs);
        }
    }
}

// ---------------------------------------------------------------------------
// helpers for gat_agg
// ---------------------------------------------------------------------------
template <int NV>
__device__ __forceinline__ uint2 ld_bf(const unsigned short* __restrict__ base, int laneoff) {
    uint2 r;
    if constexpr (NV == 4) r = *(const uint2*)(base + laneoff);
    else { r.x = *(const unsigned int*)(base + laneoff); r.y = 0; }
    return r;
}
template <int G>
__device__ __forceinline__ float grp_reduce(float vs) {
    vs = dpp_add<0xB1>(vs);              // xor 1
    vs = dpp_add<0x4E>(vs);              // xor 2
    vs = dpp_add<0x141>(vs);             // xor 4 (row_half_mirror)
    if constexpr (G >= 16) vs = dpp_add<0x140>(vs);   // xor 8 (row_mirror)
    if constexpr (G >= 32) {             // xor 16
        int t = __builtin_amdgcn_ds_swizzle(__float_as_int(vs), 0x401F);
        vs += __int_as_float(t);
    }
    if constexpr (G >= 64) vs += __shfl_xor(vs, 32, 64);
    return vs;
}

// ---------------------------------------------------------------------------
// Kernel 5: fused GATv2 gather(bf16) + score + softmax + aggregate + relu.
// One wave per dst node; xl/xr interleaved rows in xlr (stride STRIDE).
// Edge (src,w) int2 batch-loaded 64/vec-load, v_readlane extraction
// (SGPR-base gathers), unroll-4 with 4 gather slots in flight.
// Channel math in f32x2 packed ops (v_pk_fma_f32 etc.):
//   leakyrelu(m)*att == att6*m + att4*|m| (slope 0.2), |m| = pk_max(m,-m).
// ---------------------------------------------------------------------------
template <int HC, int STRIDE, int C, bool OUT_BF16>
__global__ void __launch_bounds__(256)
gat_agg(const unsigned short* __restrict__ xlr,
        const float* __restrict__ We, const float* __restrict__ att,
        const float* __restrict__ bias,
        const int* __restrict__ row_ptr, const int2* __restrict__ spk,
        const float* __restrict__ ea_loop,
        void* __restrict__ out, int n) {
    constexpr int NV = HC / 64;      // channels per lane
    constexpr int NP = NV / 2;       // f32x2 pairs per lane
    constexpr int G  = C / NV;       // lanes per head
    int wave = threadIdx.x >> 6;
    int lane = threadIdx.x & 63;
    int node = blockIdx.x * 4 + wave;
    if (node >= n) return;
    int laneoff = lane * NV;

    f32x2 xr2[NP], We2[NP], a6[NP], a4[NP], o2[NP];
    {
        uint2 u = ld_bf<NV>(xlr + (size_t)node * STRIDE + HC, laneoff);
        xr2[0] = bfpair(u.x);
        if constexpr (NP == 2) xr2[1] = bfpair(u.y);
    }
    if constexpr (NP == 2) {
        float4 t = *(const float4*)(We + laneoff);
        We2[0] = f32x2{t.x, t.y}; We2[1] = f32x2{t.z, t.w};
        float4 a = *(const float4*)(att + laneoff);
        a6[0] = f32x2{0.6f * a.x, 0.6f * a.y}; a6[1] = f32x2{0.6f * a.z, 0.6f * a.w};
        a4[0] = f32x2{0.4f * a.x, 0.4f * a.y}; a4[1] = f32x2{0.4f * a.z, 0.4f * a.w};
    } else {
        float2 t = *(const float2*)(We + laneoff);
        We2[0] = f32x2{t.x, t.y};
        float2 a = *(const float2*)(att + laneoff);
        a6[0] = f32x2{0.6f * a.x, 0.6f * a.y};
        a4[0] = f32x2{0.4f * a.x, 0.4f * a.y};
    }
#pragma unroll
    for (int p = 0; p < NP; ++p) o2[p] = f32x2{0.0f, 0.0f};

    int start = __builtin_amdgcn_readfirstlane(row_ptr[node]);
    int end   = __builtin_amdgcn_readfirstlane(row_ptr[node + 1]);
    float ea_l = ea_loop[node];
    float l = 0.0f;

    auto process = [&](uint2 xu, float w) {
        f32x2 w2 = f32x2{w, w};
        f32x2 xf[NP];
        xf[0] = bfpair(xu.x);
        if constexpr (NP == 2) xf[1] = bfpair(xu.y);
        f32x2 vs2;
#pragma unroll
        for (int p = 0; p < NP; ++p) {
            f32x2 mm = xf[p] + __builtin_elementwise_fma(w2, We2[p], xr2[p]);
            f32x2 am = __builtin_elementwise_max(mm, -mm);
            if (p == 0) vs2 = a6[0] * mm;
            else        vs2 = __builtin_elementwise_fma(a6[p], mm, vs2);
            vs2 = __builtin_elementwise_fma(a4[p], am, vs2);
        }
        float vs = vs2.x + vs2.y;
        vs = grp_reduce<G>(vs);
        float pr = __expf(vs);
        l += pr;
        f32x2 pr2 = f32x2{pr, pr};
#pragma unroll
        for (int p = 0; p < NP; ++p) o2[p] = __builtin_elementwise_fma(pr2, xf[p], o2[p]);
    };

    // ---- self-loop edge ----
    process(ld_bf<NV>(xlr + (size_t)node * STRIDE, laneoff), ea_l);

    // ---- real edges, batches of 64, unroll-4 with 4 slots in flight ----
    int cnt = end - start;
    for (int b0 = 0; b0 < cnt; b0 += 64) {
        int rem = imin(64, cnt - b0);
        int idx = start + b0 + lane;
        int idxc = imin(idx, end - 1);
        int2 pv = spk[idxc];

        auto rl = [&](int j) {
            int s = __builtin_amdgcn_readlane(pv.x, j);
            return ld_bf<NV>(xlr + (size_t)s * STRIDE, laneoff);
        };
        auto rw = [&](int j) {
            return __int_as_float(__builtin_amdgcn_readlane(pv.y, j));
        };

        int rc = rem - 1;
        uint2 X0 = rl(0),            X1 = rl(imin(1, rc)),
              X2 = rl(imin(2, rc)),  X3 = rl(imin(3, rc));
        float W0 = rw(0),            W1 = rw(imin(1, rc)),
              W2 = rw(imin(2, rc)),  W3 = rw(imin(3, rc));

        int j = 0;
        for (; j + 4 <= rem; j += 4) {
            uint2 Y0 = rl(imin(j + 4, rc)), Y1 = rl(imin(j + 5, rc)),
                  Y2 = rl(imin(j + 6, rc)), Y3 = rl(imin(j + 7, rc));
            float U0 = rw(imin(j + 4, rc)), U1 = rw(imin(j + 5, rc)),
                  U2 = rw(imin(j + 6, rc)), U3 = rw(imin(j + 7, rc));
            process(X0, W0); process(X1, W1); process(X2, W2); process(X3, W3);
            X0 = Y0; X1 = Y1; X2 = Y2; X3 = Y3;
            W0 = U0; W1 = U1; W2 = U2; W3 = U3;
        }
        if (j < rem) {
            process(X0, W0);
            if (j + 1 < rem) {
                process(X1, W1);
                if (j + 2 < rem) process(X2, W2);
            }
        }
    }

    float inv = 1.0f / (l + 1e-16f);
    float v[NV];
    if constexpr (NP == 2) {
        float4 b = *(const float4*)(bias + laneoff);
        v[0] = fmaxf(o2[0].x * inv + b.x, 0.0f);
        v[1] = fmaxf(o2[0].y * inv + b.y, 0.0f);
        v[2] = fmaxf(o2[1].x * inv + b.z, 0.0f);
        v[3] = fmaxf(o2[1].y * inv + b.w, 0.0f);
    } else {
        float2 b = *(const float2*)(bias + laneoff);
        v[0] = fmaxf(o2[0].x * inv + b.x, 0.0f);
        v[1] = fmaxf(o2[0].y * inv + b.y, 0.0f);
    }

    if constexpr (OUT_BF16) {
        unsigned short* op = (unsigned short*)out + (size_t)node * HC + laneoff;
        if constexpr (NV == 4) {
            uint2 t;
            t.x = f2bf(v[0]) | (f2bf(v[1]) << 16);
            t.y = f2bf(v[2]) | (f2bf(v[3]) << 16);
            *(uint2*)op = t;
        } else {
            *(unsigned int*)op = f2bf(v[0]) | (f2bf(v[1]) << 16);
        }
    } else {
        float* op = (float*)out + (size_t)node * HC + laneoff;
        if constexpr (NV == 4) { *(float4*)op = make_float4(v[0], v[1], v[2], v[3]); }
        else                   { *(float2*)op = make_float2(v[0], v[1]); }
    }
}

// ---------------------------------------------------------------------------
// Kernel 6: column partial sums of h2 [n,128] -> partial[gridDim.x*128]
// ---------------------------------------------------------------------------
__global__ void pool_partial(const float* __restrict__ h2, float* __restrict__ partial, int n) {
    int t = threadIdx.x;
    float s = 0.0f;
    for (int r = blockIdx.x; r < n; r += gridDim.x) s += h2[(size_t)r * 128 + t];
    partial[blockIdx.x * 128 + t] = s;
}

// ---------------------------------------------------------------------------
// Kernel 7: finish pooling, softmax over 128, sigmoid(alpha). 1024 threads.
// ---------------------------------------------------------------------------
__global__ void __launch_bounds__(1024)
pool_final(const float* __restrict__ partial, int nb,
           const float* __restrict__ alpha_in,
           float* __restrict__ out, int n) {
    __shared__ float acc[8][128];
    __shared__ float red[4];
    int t = threadIdx.x & 127;        // column
    int g = threadIdx.x >> 7;         // group 0..7
    float s = 0.0f;
    for (int b = g; b < nb; b += 8) s += partial[b * 128 + t];
    acc[g][t] = s;
    __syncthreads();
    if (threadIdx.x < 128) {
        float tot = 0.0f;
#pragma unroll
        for (int k = 0; k < 8; ++k) tot += acc[k][t];
        float mean = tot / (float)n;
        float mx = mean;
#pragma unroll
        for (int off = 32; off > 0; off >>= 1) mx = fmaxf(mx, __shfl_xor(mx, off, 64));
        if ((t & 63) == 0) red[t >> 6] = mx;
        __syncthreads();
        mx = fmaxf(red[0], red[1]);
        float ex = __expf(mean - mx);
        float sm = ex;
#pragma unroll
        for (int off = 32; off > 0; off >>= 1) sm += __shfl_xor(sm, off, 64);
        if ((t & 63) == 0) red[2 + (t >> 6)] = sm;
        __syncthreads();
        sm = red[2] + red[3];
        out[t] = ex / sm;
        if (t == 0) out[128] = 1.0f / (1.0f + __expf(-alpha_in[0]));
    }
}

// ---------------------------------------------------------------------------
extern "C" void kernel_launch(void* const* d_in, const int* in_sizes, int n_in,
                              void* d_out, int out_size, void* d_ws, size_t ws_size,
                              hipStream_t stream) {
    const float* x    = (const float*)d_in[0];
    const int*   ei   = (const int*)d_in[1];
    const float* ea   = (const float*)d_in[2];
    const float* W1l  = (const float*)d_in[3];
    const float* b1l  = (const float*)d_in[4];
    const float* W1r  = (const float*)d_in[5];
    const float* b1r  = (const float*)d_in[6];
    const float* We1  = (const float*)d_in[7];
    const float* att1 = (const float*)d_in[8];
    const float* bias1= (const float*)d_in[9];
    const float* W2l  = (const float*)d_in[10];
    const float* b2l  = (const float*)d_in[11];
    const float* W2r  = (const float*)d_in[12];
    const float* b2r  = (const float*)d_in[13];
    const float* We2  = (const float*)d_in[14];
    const float* att2 = (const float*)d_in[15];
    const float* bias2= (const float*)d_in[16];
    const float* alpha= (const float*)d_in[17];
    float* out = (float*)d_out;

    const int F = 128, HC1 = 256, HC2 = 128;
    const int n = in_sizes[0] / F;       // 20000
    const int E = in_sizes[1] / 2;       // 640000
    const int B = (n + 1023) / 1024;     // scan blocks

    char* ws = (char*)d_ws;
    size_t off = 0;
    auto alloc = [&](size_t bytes) { size_t p = off; off += (bytes + 255) & ~(size_t)255; return p; };

    unsigned long long* hist = (unsigned long long*)(ws + alloc((size_t)n * 8 * 8));  // padded x8
    int*   row_ptr = (int*)  (ws + alloc((size_t)(n + 1) * 4));
    int*   wptr    = (int*)  (ws + alloc((size_t)n * 16 * 4));                        // padded x16
    float* ea_loop = (float*)(ws + alloc((size_t)n * 4));
    int*   bsum    = (int*)  (ws + alloc(64 * 4));
    int2*  spk     = (int2*) (ws + alloc((size_t)E * 8));
    unsigned short* xb   = (unsigned short*)(ws + alloc((size_t)n * F * 2));
    unsigned short* Wt1  = (unsigned short*)(ws + alloc((size_t)F * (2 * HC1) * 2));
    unsigned short* Wt2  = (unsigned short*)(ws + alloc((size_t)HC1 * (2 * HC2) * 2));
    float* b1cat   = (float*)(ws + alloc((size_t)2 * HC1 * 4));
    float* b2cat   = (float*)(ws + alloc((size_t)2 * HC2 * 4));
    unsigned short* xlr1 = (unsigned short*)(ws + alloc((size_t)n * 2 * HC1 * 2));
    unsigned short* h1   = (unsigned short*)(ws + alloc((size_t)n * HC1 * 2));
    float* h2      = (float*)(ws + alloc((size_t)n * HC2 * 4));
    float* partial = (float*)(ws + alloc((size_t)256 * 128 * 4));
    unsigned short* xlr2 = xlr1;   // layer-2 projections alias layer-1 buffer
    const int NB_POOL = 256;

    (void)hipMemsetAsync(hist, 0, (size_t)n * 8 * 8, stream);

    int tb = 256;
    edge_hist<<<(E + tb - 1) / tb, tb, 0, stream>>>(ei, ea, hist, E);
    scan_a<<<B, 256, 0, stream>>>(hist, bsum, n);
    scan_b<<<1, 64, 0, stream>>>(bsum, row_ptr, B, n);
    scan_c<<<B, 256, 0, stream>>>(hist, bsum, row_ptr, wptr, ea_loop, n);
    edge_scatter<<<(E + tb - 1) / tb, tb, 0, stream>>>(ei, ea, wptr, spk, E);

    cvt_bf16_v4<<<(n * F / 4 + tb - 1) / tb, tb, 0, stream>>>(x, xb, n * F / 4);
    {
        int total = 2 * F * HC1 + 2 * HC1 * HC2 + 2 * HC1 + 2 * HC2;
        prep_weights<<<(total + tb - 1) / tb, tb, 0, stream>>>(
            W1l, W1r, W2l, W2r, b1l, b1r, b2l, b2r, Wt1, Wt2, b1cat, b2cat, F, HC1, HC2);
    }

    // layer 1: one merged GEMM [n,128]@[128,512] -> xlr1 (xl | xr rows)
    {
        dim3 grid((n + 63) / 64, (2 * HC1) / 64);
        gemm_bf16<<<grid, 256, 0, stream>>>(xb, Wt1, b1cat, xlr1, n, 2 * HC1, F);
    }
    gat_agg<256, 512, 32, true><<<(n + 3) / 4, 256, 0, stream>>>(
        xlr1, We1, att1, bias1, row_ptr, spk, ea_loop, h1, n);

    // layer 2: one merged GEMM [n,256]@[256,256] -> xlr2
    {
        dim3 grid((n + 63) / 64, (2 * HC2) / 64);
        gemm_bf16<<<grid, 256, 0, stream>>>(h1, Wt2, b2cat, xlr2, n, 2 * HC2, HC1);
    }
    gat_agg<128, 256, 128, false><<<(n + 3) / 4, 256, 0, stream>>>(
        xlr2, We2, att2, bias2, row_ptr, spk, ea_loop, h2, n);

    pool_partial<<<NB_POOL, 128, 0, stream>>>(h2, partial, n);
    pool_final<<<1, 1024, 0, stream>>>(partial, NB_POOL, alpha, out, n);
}